// Round 3
// baseline (10534.504 us; speedup 1.0000x reference)
//
#include <hip/hip_runtime.h>
#include <math.h>

// LSTMEncoder: N=2048 rows, T=128, H=256. Input path folded: W_comb[1024][6],
// b_comb. Decomposition: 256 blocks = 8 gate-column-groups x 32 row-groups
// (64 rows, 32 h-cols each). W_hh slice persistent in VGPRs (128/lane).
// Per-step h exchange THROUGH the out tensor (h(t) == out[:,t,:]) with a
// device-scope 8-block row-group barrier. bid = jg*32+rg => row-group blocks
// share bid%8 => same XCD => exchange + atomics are L2-local.

#define TT 128
#define NH 256

typedef __attribute__((ext_vector_type(4))) float f32x4;
typedef __attribute__((ext_vector_type(8))) short s16x8;

// ws layout (bytes):
//   [0, 524288)        wsW : 512 fragments x 64 lanes x 8 bf16
//   [524288, 548864)   wcP : [q*6+f][256] fp32 folded input weights
//   [548864, 552960)   bcP : [q][256] fp32 folded bias
//   [552960, 569344)   cnt : [128][32] u32 row-group barrier counters
#define OFF_WC 524288
#define OFF_BC 548864
#define OFF_CNT 552960

__device__ __forceinline__ unsigned short f2bf(float x) {
    unsigned u = __float_as_uint(x);
    return (unsigned short)((u + 0x7FFFu + ((u >> 16) & 1u)) >> 16);
}

__global__ void prep(const float* __restrict__ W_emb, const float* __restrict__ b_emb,
                     const float* __restrict__ W_ih,  const float* __restrict__ W_hh,
                     const float* __restrict__ b_ih,  const float* __restrict__ b_hh,
                     unsigned short* __restrict__ wsW, float* __restrict__ wcP,
                     float* __restrict__ bcP)
{
    int tid = blockIdx.x * 256 + threadIdx.x;
    if (tid < 32768) {
        // fragment fid = (cg*4+q)*8+kt ; lane l: row g = q*256+cg*16+(l&15),
        // k0 = kt*32+(l>>4)*8  (8 bf16 contiguous)
        int l   = tid & 63;
        int fid = tid >> 6;
        int kt  = fid & 7;
        int ntg = fid >> 3;
        int q   = ntg & 3;
        int cg  = ntg >> 2;
        int g   = q * 256 + cg * 16 + (l & 15);
        int k0  = kt * 32 + (l >> 4) * 8;
        const float* src = &W_hh[g * 256 + k0];
        union { unsigned short u16[8]; uint4 v; } pk;
        #pragma unroll
        for (int i = 0; i < 8; ++i) pk.u16[i] = f2bf(src[i]);
        *reinterpret_cast<uint4*>(&wsW[(size_t)fid * 512 + l * 8]) = pk.v;
    } else if (tid < 32768 + 1024) {
        int g = tid - 32768;
        float accf[6] = {0.f, 0.f, 0.f, 0.f, 0.f, 0.f};
        float accb = 0.f;
        for (int e = 0; e < 256; ++e) {
            float w = W_ih[g * 256 + e];
            accb += w * b_emb[e];
            #pragma unroll
            for (int f = 0; f < 6; ++f) accf[f] += w * W_emb[e * 6 + f];
        }
        int q = g >> 8, j = g & 255;
        #pragma unroll
        for (int f = 0; f < 6; ++f) wcP[(q * 6 + f) * 256 + j] = accf[f];
        bcP[q * 256 + j] = accb + b_ih[g] + b_hh[g];
    }
}

__device__ __forceinline__ float sigmoidf_(float x) { return 1.f / (1.f + __expf(-x)); }
__device__ __forceinline__ float tanhf_(float x) {
    float e = __expf(-2.f * fabsf(x));
    float r = (1.f - e) / (1.f + e);
    return copysignf(r, x);
}

__global__ __launch_bounds__(512, 2)
void lstm_main(const float* __restrict__ xin, const unsigned short* __restrict__ wsW,
               const float* __restrict__ wcP, const float* __restrict__ bcP,
               float* __restrict__ out, unsigned int* __restrict__ cnt)
{
    __shared__ __align__(16) unsigned short hsh[64][264];  // 33.8 KB, +16B row pad

    const int tid = threadIdx.x;
    const int w   = tid >> 6, l = tid & 63;
    const int l16 = l & 15,  lg = l >> 4;
    const int jg  = blockIdx.x >> 5;      // 0..7  column group
    const int rg  = blockIdx.x & 31;      // 0..31 row group (same XCD across jg)
    const int wm  = w & 3;                // M-tile 0..3
    const int wn  = w >> 2;               // N-half 0..1
    const int n0  = rg * 64;
    const int cg  = jg * 2 + wn;          // 0..15
    const int j   = cg * 16 + l16;        // this lane's hidden unit
    const int rbase = n0 + wm * 16 + lg * 4;  // lane's 4 batch rows: rbase..rbase+3

    // ---- persistent W fragments: 32 x s16x8 = 128 VGPR, loaded ONCE ----
    s16x8 Wf[4][8];
    #pragma unroll
    for (int q = 0; q < 4; ++q)
        #pragma unroll
        for (int kt = 0; kt < 8; ++kt)
            Wf[q][kt] = *reinterpret_cast<const s16x8*>(
                &wsW[(size_t)((cg * 4 + q) * 8 + kt) * 512 + l * 8]);

    // ---- folded input-path weights (lane-local j) ----
    float wc[4][6], bcr[4];
    #pragma unroll
    for (int q = 0; q < 4; ++q) {
        #pragma unroll
        for (int f = 0; f < 6; ++f) wc[q][f] = wcP[(q * 6 + f) * 256 + j];
        bcr[q] = bcP[q * 256 + j];
    }

    // x regs + initial pre -> acc(t=0)
    float xr[4][6];
    #pragma unroll
    for (int r = 0; r < 4; ++r)
        #pragma unroll
        for (int f = 0; f < 6; ++f) xr[r][f] = xin[((size_t)(rbase + r) * TT + 0) * 6 + f];

    f32x4 acc[4];
    #pragma unroll
    for (int q = 0; q < 4; ++q) {
        #pragma unroll
        for (int r = 0; r < 4; ++r) {
            float s = bcr[q];
            #pragma unroll
            for (int f = 0; f < 6; ++f) s = fmaf(wc[q][f], xr[r][f], s);
            acc[q][r] = s;
        }
    }
    #pragma unroll
    for (int r = 0; r < 4; ++r)
        #pragma unroll
        for (int f = 0; f < 6; ++f) xr[r][f] = xin[((size_t)(rbase + r) * TT + 1) * 6 + f];

    float c_[4] = {0.f, 0.f, 0.f, 0.f};

    const int ri = tid >> 3;              // staging: row 0..63
    const int ci = (tid & 7) * 32;        // staging: col chunk

    for (int t = 0; t < TT; ++t) {
        if (t > 0) {
            // ---- wait for row-group to finish step t-1 ----
            if (tid == 0) {
                long iter = 0;
                while (__hip_atomic_load(&cnt[(t - 1) * 32 + rg], __ATOMIC_ACQUIRE,
                                         __HIP_MEMORY_SCOPE_AGENT) < 8u) {
                    __builtin_amdgcn_s_sleep(2);
                    if (++iter > (1L << 24)) break;   // fail loud (absmax), not hang
                }
            }
            __syncthreads();
            __threadfence();   // acquire: invalidate L1/L2 view of remote h writes

            // ---- stage h(t-1) = out[:, t-1, :] rows n0..n0+63 -> LDS bf16 ----
            const float* src = out + ((size_t)(n0 + ri) * TT + (t - 1)) * NH + ci;
            unsigned short* dst = &hsh[ri][ci];
            #pragma unroll
            for (int g4 = 0; g4 < 4; ++g4) {
                float4 a = *reinterpret_cast<const float4*>(src + g4 * 8);
                float4 b = *reinterpret_cast<const float4*>(src + g4 * 8 + 4);
                union { unsigned short u16[8]; uint4 v; } pk;
                pk.u16[0] = f2bf(a.x); pk.u16[1] = f2bf(a.y);
                pk.u16[2] = f2bf(a.z); pk.u16[3] = f2bf(a.w);
                pk.u16[4] = f2bf(b.x); pk.u16[5] = f2bf(b.y);
                pk.u16[6] = f2bf(b.z); pk.u16[7] = f2bf(b.w);
                *reinterpret_cast<uint4*>(dst + g4 * 8) = pk.v;
            }
            __syncthreads();

            // ---- recurrent GEMM: acc += h(t-1) @ Wslice^T ----
            #pragma unroll
            for (int kt = 0; kt < 8; ++kt) {
                s16x8 a = *reinterpret_cast<const s16x8*>(&hsh[wm * 16 + l16][kt * 32 + lg * 8]);
                #pragma unroll
                for (int q = 0; q < 4; ++q)
                    acc[q] = __builtin_amdgcn_mfma_f32_16x16x32_bf16(a, Wf[q][kt], acc[q], 0, 0, 0);
            }
        }

        // ---- lane-local elementwise; h written straight into out (f32) ----
        #pragma unroll
        for (int r = 0; r < 4; ++r) {
            float gi = sigmoidf_(acc[0][r]);
            float gf = sigmoidf_(acc[1][r]);
            float gg = tanhf_  (acc[2][r]);
            float go = sigmoidf_(acc[3][r]);
            float cn = fmaf(gf, c_[r], gi * gg);
            c_[r] = cn;
            float hn = go * tanhf_(cn);
            out[((size_t)(rbase + r) * TT + t) * NH + j] = hn;
        }

        if (t < TT - 1) {
            // ---- publish h(t): drain stores device-visibly, then arrive ----
            __threadfence();
            __syncthreads();
            if (tid == 0)
                __hip_atomic_fetch_add(&cnt[t * 32 + rg], 1u, __ATOMIC_RELEASE,
                                       __HIP_MEMORY_SCOPE_AGENT);

            // ---- next-step input projection into acc (x-path, no h dep) ----
            #pragma unroll
            for (int q = 0; q < 4; ++q) {
                #pragma unroll
                for (int r = 0; r < 4; ++r) {
                    float s = bcr[q];
                    #pragma unroll
                    for (int f = 0; f < 6; ++f) s = fmaf(wc[q][f], xr[r][f], s);
                    acc[q][r] = s;
                }
            }
            if (t + 2 < TT) {
                #pragma unroll
                for (int r = 0; r < 4; ++r)
                    #pragma unroll
                    for (int f = 0; f < 6; ++f)
                        xr[r][f] = xin[((size_t)(rbase + r) * TT + (t + 2)) * 6 + f];
            }
        }
    }
}

extern "C" void kernel_launch(void* const* d_in, const int* in_sizes, int n_in,
                              void* d_out, int out_size, void* d_ws, size_t ws_size,
                              hipStream_t stream)
{
    const float* xin   = (const float*)d_in[0];
    const float* W_emb = (const float*)d_in[1];
    const float* b_emb = (const float*)d_in[2];
    const float* W_ih  = (const float*)d_in[3];
    const float* W_hh  = (const float*)d_in[4];
    const float* b_ih  = (const float*)d_in[5];
    const float* b_hh  = (const float*)d_in[6];
    float* out = (float*)d_out;

    unsigned short* wsW = (unsigned short*)d_ws;
    float* wcP = (float*)((char*)d_ws + OFF_WC);
    float* bcP = (float*)((char*)d_ws + OFF_BC);
    unsigned int* cnt = (unsigned int*)((char*)d_ws + OFF_CNT);

    hipMemsetAsync(cnt, 0, 128 * 32 * sizeof(unsigned int), stream);
    prep<<<132, 256, 0, stream>>>(W_emb, b_emb, W_ih, W_hh, b_ih, b_hh, wsW, wcP, bcP);
    lstm_main<<<256, 512, 0, stream>>>(xin, wsW, wcP, bcP, out, cnt);
}

// Round 4
// 1142.006 us; speedup vs baseline: 9.2246x; 9.2246x over previous
//
#include <hip/hip_runtime.h>
#include <math.h>

// LSTMEncoder: N=2048 rows, T=128, H=256. Input path folded: W_comb[1024][6].
// 256 blocks = 8 gate-column-groups (jg) x 32 row-groups (rg); W_hh slice
// persistent in VGPRs (128/lane, loaded once). Per-step h exchange THROUGH the
// out tensor (h(t) == out[:,t,:]) using device-coherent sc0/sc1 loads+stores
// (meet at Infinity Cache) + a relaxed-atomic 8-block arrive counter.
// NO __threadfence / buffer_inv / buffer_wbl2 => L2 stays warm.

#define TT 128
#define NH 256

typedef __attribute__((ext_vector_type(4))) float f32x4;
typedef __attribute__((ext_vector_type(8))) short s16x8;

// ws layout (bytes):
//   [0, 524288)        wsW : 512 fragments x 64 lanes x 8 bf16
//   [524288, 548864)   wcP : [q*6+f][256] fp32 folded input weights
//   [548864, 552960)   bcP : [q][256] fp32 folded bias
//   [552960, 569344)   cnt : [128][32] u32 row-group arrive counters
#define OFF_WC 524288
#define OFF_BC 548864
#define OFF_CNT 552960

__device__ __forceinline__ unsigned short f2bf(float x) {
    unsigned u = __float_as_uint(x);
    return (unsigned short)((u + 0x7FFFu + ((u >> 16) & 1u)) >> 16);
}

__global__ void prep(const float* __restrict__ W_emb, const float* __restrict__ b_emb,
                     const float* __restrict__ W_ih,  const float* __restrict__ W_hh,
                     const float* __restrict__ b_ih,  const float* __restrict__ b_hh,
                     unsigned short* __restrict__ wsW, float* __restrict__ wcP,
                     float* __restrict__ bcP)
{
    int tid = blockIdx.x * 256 + threadIdx.x;
    if (tid < 32768) {
        // fragment fid=(cg*4+q)*8+kt ; lane l: row g=q*256+cg*16+(l&15),
        // k0=kt*32+(l>>4)*8 (8 contiguous bf16)
        int l   = tid & 63;
        int fid = tid >> 6;
        int kt  = fid & 7;
        int ntg = fid >> 3;
        int q   = ntg & 3;
        int cg  = ntg >> 2;
        int g   = q * 256 + cg * 16 + (l & 15);
        int k0  = kt * 32 + (l >> 4) * 8;
        const float* src = &W_hh[g * 256 + k0];
        union { unsigned short u16[8]; uint4 v; } pk;
        #pragma unroll
        for (int i = 0; i < 8; ++i) pk.u16[i] = f2bf(src[i]);
        *reinterpret_cast<uint4*>(&wsW[(size_t)fid * 512 + l * 8]) = pk.v;
    } else if (tid < 32768 + 1024) {
        int g = tid - 32768;
        float accf[6] = {0.f, 0.f, 0.f, 0.f, 0.f, 0.f};
        float accb = 0.f;
        for (int e = 0; e < 256; ++e) {
            float w = W_ih[g * 256 + e];
            accb += w * b_emb[e];
            #pragma unroll
            for (int f = 0; f < 6; ++f) accf[f] += w * W_emb[e * 6 + f];
        }
        int q = g >> 8, j = g & 255;
        #pragma unroll
        for (int f = 0; f < 6; ++f) wcP[(q * 6 + f) * 256 + j] = accf[f];
        bcP[q * 256 + j] = accb + b_ih[g] + b_hh[g];
    }
}

__device__ __forceinline__ float sigmoidf_(float x) { return 1.f / (1.f + __expf(-x)); }
__device__ __forceinline__ float tanhf_(float x) {
    float e = __expf(-2.f * fabsf(x));
    float r = (1.f - e) / (1.f + e);
    return copysignf(r, x);
}

// 8 device-coherent 16B loads (32 consecutive f32), one waitcnt.
__device__ __forceinline__ void ld_dev_8x4(const float* p, float4 v[8]) {
    asm volatile(
        "global_load_dwordx4 %0, %8, off sc0 sc1\n\t"
        "global_load_dwordx4 %1, %8, off offset:16 sc0 sc1\n\t"
        "global_load_dwordx4 %2, %8, off offset:32 sc0 sc1\n\t"
        "global_load_dwordx4 %3, %8, off offset:48 sc0 sc1\n\t"
        "global_load_dwordx4 %4, %8, off offset:64 sc0 sc1\n\t"
        "global_load_dwordx4 %5, %8, off offset:80 sc0 sc1\n\t"
        "global_load_dwordx4 %6, %8, off offset:96 sc0 sc1\n\t"
        "global_load_dwordx4 %7, %8, off offset:112 sc0 sc1\n\t"
        "s_waitcnt vmcnt(0)"
        : "=v"(v[0]), "=v"(v[1]), "=v"(v[2]), "=v"(v[3]),
          "=v"(v[4]), "=v"(v[5]), "=v"(v[6]), "=v"(v[7])
        : "v"(p)
        : "memory");
}

__device__ __forceinline__ void st_dev_f32(float* p, float x) {
    asm volatile("global_store_dword %0, %1, off sc0 sc1" :: "v"(p), "v"(x) : "memory");
}

__global__ __launch_bounds__(512, 2)
void lstm_main(const float* __restrict__ xin, const unsigned short* __restrict__ wsW,
               const float* __restrict__ wcP, const float* __restrict__ bcP,
               float* __restrict__ out, unsigned int* __restrict__ cnt)
{
    __shared__ __align__(16) unsigned short hsh[64][264];  // +16B row pad

    const int tid = threadIdx.x;
    const int w   = tid >> 6, l = tid & 63;
    const int l16 = l & 15,  lg = l >> 4;
    const int jg  = blockIdx.x >> 5;      // 0..7  column group
    const int rg  = blockIdx.x & 31;      // 0..31 row group
    const int wm  = w & 3;                // M-tile
    const int wn  = w >> 2;               // N-half
    const int n0  = rg * 64;
    const int cg  = jg * 2 + wn;          // 0..15
    const int j   = cg * 16 + l16;        // lane's hidden unit
    const int rbase = n0 + wm * 16 + lg * 4;

    // ---- persistent W fragments: 32 x s16x8 = 128 VGPR, loaded ONCE ----
    s16x8 Wf[4][8];
    #pragma unroll
    for (int q = 0; q < 4; ++q)
        #pragma unroll
        for (int kt = 0; kt < 8; ++kt)
            Wf[q][kt] = *reinterpret_cast<const s16x8*>(
                &wsW[(size_t)((cg * 4 + q) * 8 + kt) * 512 + l * 8]);

    // ---- folded input-path weights (lane-local j) ----
    float wc[4][6], bcr[4];
    #pragma unroll
    for (int q = 0; q < 4; ++q) {
        #pragma unroll
        for (int f = 0; f < 6; ++f) wc[q][f] = wcP[(q * 6 + f) * 256 + j];
        bcr[q] = bcP[q * 256 + j];
    }

    float xr[4][6];
    #pragma unroll
    for (int r = 0; r < 4; ++r)
        #pragma unroll
        for (int f = 0; f < 6; ++f) xr[r][f] = xin[((size_t)(rbase + r) * TT + 0) * 6 + f];

    f32x4 acc[4];
    #pragma unroll
    for (int q = 0; q < 4; ++q) {
        #pragma unroll
        for (int r = 0; r < 4; ++r) {
            float s = bcr[q];
            #pragma unroll
            for (int f = 0; f < 6; ++f) s = fmaf(wc[q][f], xr[r][f], s);
            acc[q][r] = s;
        }
    }
    #pragma unroll
    for (int r = 0; r < 4; ++r)
        #pragma unroll
        for (int f = 0; f < 6; ++f) xr[r][f] = xin[((size_t)(rbase + r) * TT + 1) * 6 + f];

    float c_[4] = {0.f, 0.f, 0.f, 0.f};

    const int ri = tid >> 3;              // staging row 0..63
    const int ci = (tid & 7) * 32;        // staging col chunk

    for (int t = 0; t < TT; ++t) {
        if (t > 0) {
            // ---- wait for row-group arrivals for step t-1 (relaxed polls) ----
            if (tid == 0) {
                long iter = 0;
                while (__hip_atomic_load(&cnt[(t - 1) * 32 + rg], __ATOMIC_RELAXED,
                                         __HIP_MEMORY_SCOPE_AGENT) < 8u) {
                    __builtin_amdgcn_s_sleep(1);
                    if (++iter > (1L << 20)) break;   // fail loud, not hang
                }
            }
            __syncthreads();

            // ---- stage h(t-1) = out[:, t-1, :] -> LDS bf16 (sc0sc1, bypass) ----
            const float* src = out + ((size_t)(n0 + ri) * TT + (t - 1)) * NH + ci;
            float4 v[8];
            ld_dev_8x4(src, v);
            unsigned short* dst = &hsh[ri][ci];
            #pragma unroll
            for (int g4 = 0; g4 < 4; ++g4) {
                float4 a = v[g4 * 2], b = v[g4 * 2 + 1];
                union { unsigned short u16[8]; uint4 q; } pk;
                pk.u16[0] = f2bf(a.x); pk.u16[1] = f2bf(a.y);
                pk.u16[2] = f2bf(a.z); pk.u16[3] = f2bf(a.w);
                pk.u16[4] = f2bf(b.x); pk.u16[5] = f2bf(b.y);
                pk.u16[6] = f2bf(b.z); pk.u16[7] = f2bf(b.w);
                *reinterpret_cast<uint4*>(dst + g4 * 8) = pk.q;
            }
            __syncthreads();

            // ---- recurrent GEMM: acc += h(t-1) @ Wslice^T ----
            #pragma unroll
            for (int kt = 0; kt < 8; ++kt) {
                s16x8 a = *reinterpret_cast<const s16x8*>(&hsh[wm * 16 + l16][kt * 32 + lg * 8]);
                #pragma unroll
                for (int q = 0; q < 4; ++q)
                    acc[q] = __builtin_amdgcn_mfma_f32_16x16x32_bf16(a, Wf[q][kt], acc[q], 0, 0, 0);
            }
        }

        // ---- lane-local elementwise; h(t) published via sc0sc1 stores ----
        #pragma unroll
        for (int r = 0; r < 4; ++r) {
            float gi = sigmoidf_(acc[0][r]);
            float gf = sigmoidf_(acc[1][r]);
            float gg = tanhf_  (acc[2][r]);
            float go = sigmoidf_(acc[3][r]);
            float cn = fmaf(gf, c_[r], gi * gg);
            c_[r] = cn;
            float hn = go * tanhf_(cn);
            st_dev_f32(&out[((size_t)(rbase + r) * TT + t) * NH + j], hn);
        }

        if (t < TT - 1) {
            // next-step x-projection (pure VALU) hides the store drain
            #pragma unroll
            for (int q = 0; q < 4; ++q) {
                #pragma unroll
                for (int r = 0; r < 4; ++r) {
                    float s = bcr[q];
                    #pragma unroll
                    for (int f = 0; f < 6; ++f) s = fmaf(wc[q][f], xr[r][f], s);
                    acc[q][r] = s;
                }
            }
            asm volatile("s_waitcnt vmcnt(0)" ::: "memory");  // h(t) in IF
            __syncthreads();
            if (tid == 0)
                __hip_atomic_fetch_add(&cnt[t * 32 + rg], 1u, __ATOMIC_RELAXED,
                                       __HIP_MEMORY_SCOPE_AGENT);
            // prefetch x(t+2); consumed late next iteration
            if (t + 2 < TT) {
                #pragma unroll
                for (int r = 0; r < 4; ++r)
                    #pragma unroll
                    for (int f = 0; f < 6; ++f)
                        xr[r][f] = xin[((size_t)(rbase + r) * TT + (t + 2)) * 6 + f];
            }
        }
    }
}

extern "C" void kernel_launch(void* const* d_in, const int* in_sizes, int n_in,
                              void* d_out, int out_size, void* d_ws, size_t ws_size,
                              hipStream_t stream)
{
    const float* xin   = (const float*)d_in[0];
    const float* W_emb = (const float*)d_in[1];
    const float* b_emb = (const float*)d_in[2];
    const float* W_ih  = (const float*)d_in[3];
    const float* W_hh  = (const float*)d_in[4];
    const float* b_ih  = (const float*)d_in[5];
    const float* b_hh  = (const float*)d_in[6];
    float* out = (float*)d_out;

    unsigned short* wsW = (unsigned short*)d_ws;
    float* wcP = (float*)((char*)d_ws + OFF_WC);
    float* bcP = (float*)((char*)d_ws + OFF_BC);
    unsigned int* cnt = (unsigned int*)((char*)d_ws + OFF_CNT);

    hipMemsetAsync(cnt, 0, 128 * 32 * sizeof(unsigned int), stream);
    prep<<<132, 256, 0, stream>>>(W_emb, b_emb, W_ih, W_hh, b_ih, b_hh, wsW, wcP, bcP);
    lstm_main<<<256, 512, 0, stream>>>(xin, wsW, wcP, bcP, out, cnt);
}